// Round 7
// baseline (374.983 us; speedup 1.0000x reference)
//
#include <hip/hip_runtime.h>

#define NN 50
#define D 64
#define GRP 10
#define EPW 4   // elements per wave (sequential) -> 16 per block

__device__ __forceinline__ float wave_sum64(float x) {
#pragma unroll
  for (int off = 32; off > 0; off >>= 1)
    x += __shfl_xor(x, off, 64);
  return x;
}

__device__ __forceinline__ float readlane_f(float v, int l) {
  return __uint_as_float(__builtin_amdgcn_readlane(__float_as_uint(v), l));
}

// Load group g's 10 neighbor rows (lane = dim). All indices compile-time.
__device__ __forceinline__ void load_grp(float (&buf)[GRP],
                                         const int* __restrict__ adjb,
                                         const float* __restrict__ ent_tab,
                                         int g, int lane) {
#pragma unroll
  for (int i = 0; i < GRP; ++i) {
    int t = adjb[g * GRP + i];
    t = t < 0 ? 0 : t;
    buf[i] = ent_tab[(long)t * D + lane];   // coalesced 256B row
  }
}

// Score + exp + accumulate for one group. buf stays in registers.
// 10 independent 6-deep butterfly chains: this ILP structure is the proven
// fast one (R3); tree/serial variants regressed badly (R4, R6).
__device__ __forceinline__ void proc_grp(const float (&buf)[GRP],
                                         float Wn, float base,
                                         float& l0, float& l1, float& na) {
  float ex[GRP];
#pragma unroll
  for (int i = 0; i < GRP; ++i) {
    float t = wave_sum64(buf[i] * Wn) + base;
    t = t > 0.f ? t : 0.2f * t;     // leaky_relu(0.2)
    ex[i] = __expf(t - 8.0f);       // fixed-max softmax: scores bounded ~[-2,8]
  }
#pragma unroll
  for (int i = 0; i < GRP; ++i) {
    if (i & 1) l1 += ex[i]; else l0 += ex[i];
    na = fmaf(ex[i], buf[i], na);
  }
}

// Full attention for one element (R3-proven double-buffered named arrays).
__device__ __forceinline__ float attn_one(const int* __restrict__ adjb,
                                          const float* __restrict__ ent_tab,
                                          float Wn, float base, int lane) {
  float na = 0.f, l0 = 0.f, l1 = 0.f;
  float A[GRP], Bv[GRP];
  load_grp(A,  adjb, ent_tab, 0, lane);
  load_grp(Bv, adjb, ent_tab, 1, lane);
  proc_grp(A,  Wn, base, l0, l1, na);
  load_grp(A,  adjb, ent_tab, 2, lane);
  proc_grp(Bv, Wn, base, l0, l1, na);
  load_grp(Bv, adjb, ent_tab, 3, lane);
  proc_grp(A,  Wn, base, l0, l1, na);
  load_grp(A,  adjb, ent_tab, 4, lane);
  proc_grp(Bv, Wn, base, l0, l1, na);
  proc_grp(A,  Wn, base, l0, l1, na);
  return na / (l0 + l1);
}

// GEMV chain + final score. cW comes from LDS (staged once per block);
// W1/W2 (32 KB combined) now fit L1 on their own.
__device__ __forceinline__ void gemv_store(
    int b, float na, float item, float user, int lane,
    const float* __restrict__ s_cW,
    const float* __restrict__ W1, const float* __restrict__ b1,
    const float* __restrict__ W2, const float* __restrict__ b2,
    const float* __restrict__ cb,
    const float* __restrict__ oW, float ob0,
    float* __restrict__ out) {
  // h = relu(na @ W1 + b1): lane owns column, 4-way accumulators
  float h0 = b1[lane], h1 = 0.f, h2 = 0.f, h3 = 0.f;
#pragma unroll
  for (int d = 0; d < D; d += 4) {
    h0 = fmaf(readlane_f(na, d + 0), W1[(d + 0) * D + lane], h0);
    h1 = fmaf(readlane_f(na, d + 1), W1[(d + 1) * D + lane], h1);
    h2 = fmaf(readlane_f(na, d + 2), W1[(d + 2) * D + lane], h2);
    h3 = fmaf(readlane_f(na, d + 3), W1[(d + 3) * D + lane], h3);
  }
  const float h = fmaxf((h0 + h1) + (h2 + h3), 0.f);

  // r = h @ W2 + b2
  float r0 = b2[lane], r1 = 0.f, r2 = 0.f, r3 = 0.f;
#pragma unroll
  for (int d = 0; d < D; d += 4) {
    r0 = fmaf(readlane_f(h, d + 0), W2[(d + 0) * D + lane], r0);
    r1 = fmaf(readlane_f(h, d + 1), W2[(d + 1) * D + lane], r1);
    r2 = fmaf(readlane_f(h, d + 2), W2[(d + 2) * D + lane], r2);
    r3 = fmaf(readlane_f(h, d + 3), W2[(d + 3) * D + lane], r3);
  }
  const float r = (r0 + r1) + (r2 + r3);

  // f = relu([item, r] @ cW + cb), cW from LDS (2-way bank alias = free)
  float f0 = cb[lane], f1 = 0.f, f2 = 0.f, f3 = 0.f;
#pragma unroll
  for (int k = 0; k < D; k += 4) {
    f0 = fmaf(readlane_f(item, k + 0), s_cW[(k + 0) * D + lane], f0);
    f1 = fmaf(readlane_f(item, k + 1), s_cW[(k + 1) * D + lane], f1);
    f2 = fmaf(readlane_f(item, k + 2), s_cW[(k + 2) * D + lane], f2);
    f3 = fmaf(readlane_f(item, k + 3), s_cW[(k + 3) * D + lane], f3);
  }
#pragma unroll
  for (int k = 0; k < D; k += 4) {
    f0 = fmaf(readlane_f(r, k + 0), s_cW[(D + k + 0) * D + lane], f0);
    f1 = fmaf(readlane_f(r, k + 1), s_cW[(D + k + 1) * D + lane], f1);
    f2 = fmaf(readlane_f(r, k + 2), s_cW[(D + k + 2) * D + lane], f2);
    f3 = fmaf(readlane_f(r, k + 3), s_cW[(D + k + 3) * D + lane], f3);
  }
  const float f = fmaxf((f0 + f1) + (f2 + f3), 0.f);

  // score = dot([user, f], oW) + ob
  const float sc = wave_sum64(fmaf(user, oW[lane], f * oW[D + lane]));
  if (lane == 0) out[b] = sc + ob0;
}

__global__ __launch_bounds__(256, 4) void kgat_fwd(
    const int* __restrict__ user_idx, const int* __restrict__ item_idx,
    const int* __restrict__ adj,
    const float* __restrict__ user_tab, const float* __restrict__ item_tab,
    const float* __restrict__ ent_tab,
    const float* __restrict__ attn_W, const float* __restrict__ attn_b,
    const float* __restrict__ W1, const float* __restrict__ b1,
    const float* __restrict__ W2, const float* __restrict__ b2,
    const float* __restrict__ cW, const float* __restrict__ cb,
    const float* __restrict__ oW, const float* __restrict__ ob,
    float* __restrict__ out, int B)
{
  __shared__ float s_cW[2 * D * D];   // 32 KB

  // ---- stage cW into LDS (float4, all 256 threads) ----
  {
    const float4* src = (const float4*)cW;
    float4* dst = (float4*)s_cW;
#pragma unroll
    for (int i = 0; i < 8; ++i)
      dst[threadIdx.x + 256 * i] = src[threadIdx.x + 256 * i];
  }

  const int lane = threadIdx.x & 63;
  const int wv   = threadIdx.x >> 6;
  const int b0   = (blockIdx.x * 4 + wv) * EPW;

  const float Wi  = attn_W[lane];
  const float Wn  = attn_W[D + lane];
  const float ab  = attn_b[0];
  const float ob0 = ob[0];

  // ---- element 0: attention BEFORE the barrier (hides staging latency) ----
  float na0 = 0.f, item0 = 0.f, user0 = 0.f;
  const bool ok0 = (b0 < B);
  if (ok0) {
    user0 = user_tab[(long)user_idx[b0] * D + lane];
    item0 = item_tab[(long)item_idx[b0] * D + lane];
    const float base = wave_sum64(item0 * Wi) + ab;
    na0 = attn_one(adj + (long)b0 * NN, ent_tab, Wn, base, lane);
  }
  __syncthreads();   // staging visible; LDS read-only from here on
  if (ok0)
    gemv_store(b0, na0, item0, user0, lane, s_cW, W1, b1, W2, b2, cb, oW, ob0, out);

  // ---- elements 1..3 sequentially (no extra live state -> no spill) ----
#pragma unroll 1
  for (int e = 1; e < EPW; ++e) {
    const int b = b0 + e;
    if (b >= B) break;
    const float user = user_tab[(long)user_idx[b] * D + lane];
    const float item = item_tab[(long)item_idx[b] * D + lane];
    const float base = wave_sum64(item * Wi) + ab;
    const float na   = attn_one(adj + (long)b * NN, ent_tab, Wn, base, lane);
    gemv_store(b, na, item, user, lane, s_cW, W1, b1, W2, b2, cb, oW, ob0, out);
  }
}

extern "C" void kernel_launch(void* const* d_in, const int* in_sizes, int n_in,
                              void* d_out, int out_size, void* d_ws, size_t ws_size,
                              hipStream_t stream) {
  const int*   user_idx = (const int*)d_in[0];
  const int*   item_idx = (const int*)d_in[1];
  const int*   adj      = (const int*)d_in[2];
  const float* user_tab = (const float*)d_in[3];
  const float* item_tab = (const float*)d_in[4];
  const float* ent_tab  = (const float*)d_in[5];
  const float* attn_W   = (const float*)d_in[6];
  const float* attn_b   = (const float*)d_in[7];
  const float* W1       = (const float*)d_in[8];
  const float* b1       = (const float*)d_in[9];
  const float* W2       = (const float*)d_in[10];
  const float* b2       = (const float*)d_in[11];
  const float* cW       = (const float*)d_in[12];
  const float* cb       = (const float*)d_in[13];
  const float* oW       = (const float*)d_in[14];
  const float* ob       = (const float*)d_in[15];
  float* out = (float*)d_out;

  const int B = in_sizes[0];
  const int per_block = 4 * EPW;                    // 16 elements per block
  const int blocks = (B + per_block - 1) / per_block;
  kgat_fwd<<<blocks, 256, 0, stream>>>(user_idx, item_idx, adj,
                                       user_tab, item_tab, ent_tab,
                                       attn_W, attn_b, W1, b1, W2, b2,
                                       cW, cb, oW, ob, out, B);
}

// Round 8
// 90.311 us; speedup vs baseline: 4.1521x; 4.1521x over previous
//
#include <hip/hip_runtime.h>

#define NN 50
#define D 64
#define GRP 10

__device__ __forceinline__ float readlane_f(float v, int l) {
  return __uint_as_float(__builtin_amdgcn_readlane(__float_as_uint(v), l));
}

// x + dpp_shifted(x): runs on the VALU pipe (no DS/ds_swizzle traffic).
// bound_ctrl=true -> out-of-range lanes contribute 0 (sum identity).
template <int CTRL>
__device__ __forceinline__ float dpp_add(float x) {
  const int t = __builtin_amdgcn_update_dpp(0, __float_as_int(x),
                                            CTRL, 0xf, 0xf, true);
  return x + __uint_as_float(t);
}

// Full 64-lane sum via DPP (row_shr prefix within rows of 16, then
// row_bcast15/31 to cross rows). Total lands in lane 63; broadcast via
// readlane -> wave-uniform (SGPR). 6 VALU adds + 1 readlane, zero DS ops.
__device__ __forceinline__ float wave_sum64(float x) {
  x = dpp_add<0x111>(x);   // row_shr:1
  x = dpp_add<0x112>(x);   // row_shr:2
  x = dpp_add<0x114>(x);   // row_shr:4
  x = dpp_add<0x118>(x);   // row_shr:8  -> lane 15 of each row has row sum
  x = dpp_add<0x142>(x);   // row_bcast15: lane31=r0+r1, lane63=r2+r3
  x = dpp_add<0x143>(x);   // row_bcast31: lane63=total
  return readlane_f(x, 63);
}

// Load group g's 10 neighbor rows (lane = dim). All indices compile-time.
__device__ __forceinline__ void load_grp(float (&buf)[GRP],
                                         const int* __restrict__ adjb,
                                         const float* __restrict__ ent_tab,
                                         int g, int lane) {
#pragma unroll
  for (int i = 0; i < GRP; ++i) {
    int t = adjb[g * GRP + i];      // wave-uniform -> s_load
    t = t < 0 ? 0 : t;
    buf[i] = ent_tab[(long)t * D + lane];   // coalesced 256B row
  }
}

// Score + exp + accumulate for one group. buf stays in registers.
// 10 independent reduce chains (proven R3 ILP structure).
__device__ __forceinline__ void proc_grp(const float (&buf)[GRP],
                                         float Wn, float base,
                                         float& l0, float& l1, float& na) {
  float ex[GRP];
#pragma unroll
  for (int i = 0; i < GRP; ++i) {
    float t = wave_sum64(buf[i] * Wn) + base;
    t = t > 0.f ? t : 0.2f * t;     // leaky_relu(0.2)
    ex[i] = __expf(t - 8.0f);       // fixed-max softmax: scores bounded ~[-2,8]
  }
#pragma unroll
  for (int i = 0; i < GRP; ++i) {
    if (i & 1) l1 += ex[i]; else l0 += ex[i];
    na = fmaf(ex[i], buf[i], na);
  }
}

__global__ __launch_bounds__(256, 4) void kgat_fwd(
    const int* __restrict__ user_idx, const int* __restrict__ item_idx,
    const int* __restrict__ adj,
    const float* __restrict__ user_tab, const float* __restrict__ item_tab,
    const float* __restrict__ ent_tab,
    const float* __restrict__ attn_W, const float* __restrict__ attn_b,
    const float* __restrict__ W1, const float* __restrict__ b1,
    const float* __restrict__ W2, const float* __restrict__ b2,
    const float* __restrict__ cW, const float* __restrict__ cb,
    const float* __restrict__ oW, const float* __restrict__ ob,
    float* __restrict__ out, int B)
{
  const int lane = threadIdx.x & 63;
  const int wv   = threadIdx.x >> 6;
  const int b    = blockIdx.x * 4 + wv;
  if (b >= B) return;

  // Hoist long-latency loads whose results are needed late.
  const float user = user_tab[(long)user_idx[b] * D + lane];
  const float oWu  = oW[lane];
  const float oWf  = oW[D + lane];

  // ---- item embedding + attention base score (uniform) ----
  const float item = item_tab[(long)item_idx[b] * D + lane];
  const float Wi   = attn_W[lane];
  const float Wn   = attn_W[D + lane];
  const float base = wave_sum64(item * Wi) + attn_b[0];

  const int* adjb = adj + b * NN;

  // ---- single-pass fixed-max softmax, double-buffered in NAMED register
  //      arrays (no computed buffer index -> guaranteed register promotion) ----
  float na = 0.f, l0 = 0.f, l1 = 0.f;
  float A[GRP], Bv[GRP];

  load_grp(A,  adjb, ent_tab, 0, lane);
  load_grp(Bv, adjb, ent_tab, 1, lane);
  proc_grp(A,  Wn, base, l0, l1, na);        // group 0
  load_grp(A,  adjb, ent_tab, 2, lane);
  proc_grp(Bv, Wn, base, l0, l1, na);        // group 1
  load_grp(Bv, adjb, ent_tab, 3, lane);
  proc_grp(A,  Wn, base, l0, l1, na);        // group 2
  load_grp(A,  adjb, ent_tab, 4, lane);
  proc_grp(Bv, Wn, base, l0, l1, na);        // group 3
  proc_grp(A,  Wn, base, l0, l1, na);        // group 4

  na /= (l0 + l1);

  // ---- h = relu(na @ W1 + b1): lane owns column, 4-way accumulators ----
  float h0 = b1[lane], h1 = 0.f, h2 = 0.f, h3 = 0.f;
#pragma unroll
  for (int d = 0; d < D; d += 4) {
    h0 = fmaf(readlane_f(na, d + 0), W1[(d + 0) * D + lane], h0);
    h1 = fmaf(readlane_f(na, d + 1), W1[(d + 1) * D + lane], h1);
    h2 = fmaf(readlane_f(na, d + 2), W1[(d + 2) * D + lane], h2);
    h3 = fmaf(readlane_f(na, d + 3), W1[(d + 3) * D + lane], h3);
  }
  const float h = fmaxf((h0 + h1) + (h2 + h3), 0.f);

  // ---- r = h @ W2 + b2 ----
  float r0 = b2[lane], r1 = 0.f, r2 = 0.f, r3 = 0.f;
#pragma unroll
  for (int d = 0; d < D; d += 4) {
    r0 = fmaf(readlane_f(h, d + 0), W2[(d + 0) * D + lane], r0);
    r1 = fmaf(readlane_f(h, d + 1), W2[(d + 1) * D + lane], r1);
    r2 = fmaf(readlane_f(h, d + 2), W2[(d + 2) * D + lane], r2);
    r3 = fmaf(readlane_f(h, d + 3), W2[(d + 3) * D + lane], r3);
  }
  const float r = (r0 + r1) + (r2 + r3);

  // ---- f = relu([item, r] @ cW + cb) ----
  float f0 = cb[lane], f1 = 0.f, f2 = 0.f, f3 = 0.f;
#pragma unroll
  for (int k = 0; k < D; k += 4) {
    f0 = fmaf(readlane_f(item, k + 0), cW[(k + 0) * D + lane], f0);
    f1 = fmaf(readlane_f(item, k + 1), cW[(k + 1) * D + lane], f1);
    f2 = fmaf(readlane_f(item, k + 2), cW[(k + 2) * D + lane], f2);
    f3 = fmaf(readlane_f(item, k + 3), cW[(k + 3) * D + lane], f3);
  }
#pragma unroll
  for (int k = 0; k < D; k += 4) {
    f0 = fmaf(readlane_f(r, k + 0), cW[(D + k + 0) * D + lane], f0);
    f1 = fmaf(readlane_f(r, k + 1), cW[(D + k + 1) * D + lane], f1);
    f2 = fmaf(readlane_f(r, k + 2), cW[(D + k + 2) * D + lane], f2);
    f3 = fmaf(readlane_f(r, k + 3), cW[(D + k + 3) * D + lane], f3);
  }
  const float f = fmaxf((f0 + f1) + (f2 + f3), 0.f);

  // ---- score = dot([user, f], oW) + ob ----
  const float sc = wave_sum64(fmaf(user, oWu, f * oWf));
  if (lane == 0) out[b] = sc + ob[0];
}

extern "C" void kernel_launch(void* const* d_in, const int* in_sizes, int n_in,
                              void* d_out, int out_size, void* d_ws, size_t ws_size,
                              hipStream_t stream) {
  const int*   user_idx = (const int*)d_in[0];
  const int*   item_idx = (const int*)d_in[1];
  const int*   adj      = (const int*)d_in[2];
  const float* user_tab = (const float*)d_in[3];
  const float* item_tab = (const float*)d_in[4];
  const float* ent_tab  = (const float*)d_in[5];
  const float* attn_W   = (const float*)d_in[6];
  const float* attn_b   = (const float*)d_in[7];
  const float* W1       = (const float*)d_in[8];
  const float* b1       = (const float*)d_in[9];
  const float* W2       = (const float*)d_in[10];
  const float* b2       = (const float*)d_in[11];
  const float* cW       = (const float*)d_in[12];
  const float* cb       = (const float*)d_in[13];
  const float* oW       = (const float*)d_in[14];
  const float* ob       = (const float*)d_in[15];
  float* out = (float*)d_out;

  const int B = in_sizes[0];
  const int blocks = (B + 3) / 4;   // 4 waves (1 element each) per block
  kgat_fwd<<<blocks, 256, 0, stream>>>(user_idx, item_idx, adj,
                                       user_tab, item_tab, ent_tab,
                                       attn_W, attn_b, W1, b1, W2, b2,
                                       cW, cb, oW, ob, out, B);
}

// Round 9
// 84.359 us; speedup vs baseline: 4.4451x; 1.0706x over previous
//
#include <hip/hip_runtime.h>

#define NN 50
#define D 64
#define GRP 10

__device__ __forceinline__ float wave_sum64(float x) {
#pragma unroll
  for (int off = 32; off > 0; off >>= 1)
    x += __shfl_xor(x, off, 64);
  return x;
}

__device__ __forceinline__ float readlane_f(float v, int l) {
  return __uint_as_float(__builtin_amdgcn_readlane(__float_as_uint(v), l));
}

// Load group g's 10 neighbor rows (lane = dim). All indices compile-time.
__device__ __forceinline__ void load_grp(float (&buf)[GRP],
                                         const int* __restrict__ adjb,
                                         const float* __restrict__ ent_tab,
                                         int g, int lane) {
#pragma unroll
  for (int i = 0; i < GRP; ++i) {
    int t = adjb[g * GRP + i];      // wave-uniform -> s_load
    t = t < 0 ? 0 : t;
    buf[i] = ent_tab[(long)t * D + lane];   // coalesced 256B row
  }
}

// ===================== precompute: proj[e] = dot(ent[e], Wn) =================
// 10 rows per wave, proven 10-parallel-butterfly structure.
__global__ __launch_bounds__(256, 4) void ent_proj(
    const float* __restrict__ ent_tab, const float* __restrict__ attn_W,
    float* __restrict__ proj, int rows)
{
  const int  lane = threadIdx.x & 63;
  const long wave = (long)blockIdx.x * 4 + (threadIdx.x >> 6);
  const long base = wave * GRP;
  if (base >= rows) return;
  const float Wn = attn_W[D + lane];
  float v[GRP];
#pragma unroll
  for (int i = 0; i < GRP; ++i) {
    long r = base + i; if (r > rows - 1) r = rows - 1;
    v[i] = ent_tab[r * D + lane];           // coalesced, contiguous rows
  }
  float s[GRP];
#pragma unroll
  for (int i = 0; i < GRP; ++i)
    s[i] = wave_sum64(v[i] * Wn);           // 10 independent butterfly chains
  if (lane == 0) {
#pragma unroll
    for (int i = 0; i < GRP; ++i)
      if (base + i < rows) proj[base + i] = s[i];
  }
}

// ========================= main kernel (proj-based) ==========================
// Weighted accumulation for one group: e holds per-lane exp(score), lane=n.
__device__ __forceinline__ void acc_grp(const float (&buf)[GRP], float e, int g,
                                        float& na0, float& na1) {
#pragma unroll
  for (int i = 0; i < GRP; ++i) {
    const float w = readlane_f(e, g * GRP + i);   // compile-time lane index
    if (i & 1) na1 = fmaf(w, buf[i], na1);
    else       na0 = fmaf(w, buf[i], na0);
  }
}

__global__ __launch_bounds__(256, 4) void kgat_main(
    const int* __restrict__ user_idx, const int* __restrict__ item_idx,
    const int* __restrict__ adj,
    const float* __restrict__ user_tab, const float* __restrict__ item_tab,
    const float* __restrict__ ent_tab, const float* __restrict__ proj,
    const float* __restrict__ attn_W, const float* __restrict__ attn_b,
    const float* __restrict__ W1, const float* __restrict__ b1,
    const float* __restrict__ W2, const float* __restrict__ b2,
    const float* __restrict__ cW, const float* __restrict__ cb,
    const float* __restrict__ oW, const float* __restrict__ ob,
    float* __restrict__ out, int B)
{
  __shared__ __align__(16) float s_act[4 * D];   // per-wave activation bcast
  __shared__ __align__(16) float s_itm[4 * D];   // per-wave item bcast

  const int lane = threadIdx.x & 63;
  const int wv   = threadIdx.x >> 6;
  const int b    = blockIdx.x * 4 + wv;
  if (b >= B) return;
  float* sa = s_act + wv * D;
  float* si = s_itm + wv * D;

  const float user = user_tab[(long)user_idx[b] * D + lane];
  const float item = item_tab[(long)item_idx[b] * D + lane];
  si[lane] = item;                                // wave-private, no barrier
  const float base = wave_sum64(item * attn_W[lane]) + attn_b[0];  // uniform

  const int* adjb = adj + b * NN;

  // ---- scores: lane n gathers proj[adj[n]] (800KB table, L2-hot) ----
  const int myn = lane < NN ? lane : NN - 1;
  int mi = adjb[myn]; mi = mi < 0 ? 0 : mi;
  float s = proj[mi] + base;
  s = s > 0.f ? s : 0.2f * s;                     // leaky_relu(0.2)
  // fixed-max softmax: scores are leaky_relu of ~unit-variance dots, bounded
  // well below 8 -> exp(s-8) can't overflow, denom can't underflow to 0.
  const float e = (lane < NN) ? __expf(s - 8.0f) : 0.f;
  const float denom = wave_sum64(e);

  // ---- weighted sum: R3-proven double-buffered coalesced row groups ----
  float na0 = 0.f, na1 = 0.f;
  float A[GRP], Bv[GRP];
  load_grp(A,  adjb, ent_tab, 0, lane);
  load_grp(Bv, adjb, ent_tab, 1, lane);
  acc_grp(A,  e, 0, na0, na1);
  load_grp(A,  adjb, ent_tab, 2, lane);
  acc_grp(Bv, e, 1, na0, na1);
  load_grp(Bv, adjb, ent_tab, 3, lane);
  acc_grp(A,  e, 2, na0, na1);
  load_grp(A,  adjb, ent_tab, 4, lane);
  acc_grp(Bv, e, 3, na0, na1);
  acc_grp(A,  e, 4, na0, na1);
  const float na = (na0 + na1) / denom;

  // ---- h = relu(na @ W1 + b1): activations broadcast from LDS (b128,
  //      uniform address = conflict-free), weights coalesced from global ----
  sa[lane] = na;
  float h0 = b1[lane], h1 = 0.f, h2 = 0.f, h3 = 0.f;
#pragma unroll
  for (int d = 0; d < D; d += 4) {
    const float4 c = *(const float4*)(sa + d);
    h0 = fmaf(c.x, W1[(d + 0) * D + lane], h0);
    h1 = fmaf(c.y, W1[(d + 1) * D + lane], h1);
    h2 = fmaf(c.z, W1[(d + 2) * D + lane], h2);
    h3 = fmaf(c.w, W1[(d + 3) * D + lane], h3);
  }
  const float h = fmaxf((h0 + h1) + (h2 + h3), 0.f);

  // ---- r = h @ W2 + b2 ----
  sa[lane] = h;
  float r0 = b2[lane], r1 = 0.f, r2 = 0.f, r3 = 0.f;
#pragma unroll
  for (int d = 0; d < D; d += 4) {
    const float4 c = *(const float4*)(sa + d);
    r0 = fmaf(c.x, W2[(d + 0) * D + lane], r0);
    r1 = fmaf(c.y, W2[(d + 1) * D + lane], r1);
    r2 = fmaf(c.z, W2[(d + 2) * D + lane], r2);
    r3 = fmaf(c.w, W2[(d + 3) * D + lane], r3);
  }
  const float r = (r0 + r1) + (r2 + r3);

  // ---- f = relu([item, r] @ cW + cb) ----
  sa[lane] = r;
  float f0 = cb[lane], f1 = 0.f, f2 = 0.f, f3 = 0.f;
#pragma unroll
  for (int k = 0; k < D; k += 4) {
    const float4 ci = *(const float4*)(si + k);
    f0 = fmaf(ci.x, cW[(k + 0) * D + lane], f0);
    f1 = fmaf(ci.y, cW[(k + 1) * D + lane], f1);
    f2 = fmaf(ci.z, cW[(k + 2) * D + lane], f2);
    f3 = fmaf(ci.w, cW[(k + 3) * D + lane], f3);
  }
#pragma unroll
  for (int k = 0; k < D; k += 4) {
    const float4 cr = *(const float4*)(sa + k);
    f0 = fmaf(cr.x, cW[(D + k + 0) * D + lane], f0);
    f1 = fmaf(cr.y, cW[(D + k + 1) * D + lane], f1);
    f2 = fmaf(cr.z, cW[(D + k + 2) * D + lane], f2);
    f3 = fmaf(cr.w, cW[(D + k + 3) * D + lane], f3);
  }
  const float f = fmaxf((f0 + f1) + (f2 + f3), 0.f);

  // ---- score = dot([user, f], oW) + ob ----
  const float sc = wave_sum64(fmaf(user, oW[lane], f * oW[D + lane]));
  if (lane == 0) out[b] = sc + ob[0];
}

// ================= fallback: exact R3 kernel (no workspace) =================
__device__ __forceinline__ void proc_grp(const float (&buf)[GRP],
                                         float Wn, float base,
                                         float& l0, float& l1, float& na) {
  float ex[GRP];
#pragma unroll
  for (int i = 0; i < GRP; ++i) {
    float t = wave_sum64(buf[i] * Wn) + base;
    t = t > 0.f ? t : 0.2f * t;
    ex[i] = __expf(t - 8.0f);
  }
#pragma unroll
  for (int i = 0; i < GRP; ++i) {
    if (i & 1) l1 += ex[i]; else l0 += ex[i];
    na = fmaf(ex[i], buf[i], na);
  }
}

__global__ __launch_bounds__(256, 4) void kgat_r3(
    const int* __restrict__ user_idx, const int* __restrict__ item_idx,
    const int* __restrict__ adj,
    const float* __restrict__ user_tab, const float* __restrict__ item_tab,
    const float* __restrict__ ent_tab,
    const float* __restrict__ attn_W, const float* __restrict__ attn_b,
    const float* __restrict__ W1, const float* __restrict__ b1,
    const float* __restrict__ W2, const float* __restrict__ b2,
    const float* __restrict__ cW, const float* __restrict__ cb,
    const float* __restrict__ oW, const float* __restrict__ ob,
    float* __restrict__ out, int B)
{
  const int lane = threadIdx.x & 63;
  const int wv   = threadIdx.x >> 6;
  const int b    = blockIdx.x * 4 + wv;
  if (b >= B) return;

  const float user = user_tab[(long)user_idx[b] * D + lane];
  const float oWu  = oW[lane];
  const float oWf  = oW[D + lane];
  const float item = item_tab[(long)item_idx[b] * D + lane];
  const float Wi   = attn_W[lane];
  const float Wn   = attn_W[D + lane];
  const float base = wave_sum64(item * Wi) + attn_b[0];
  const int* adjb = adj + b * NN;

  float na = 0.f, l0 = 0.f, l1 = 0.f;
  float A[GRP], Bv[GRP];
  load_grp(A,  adjb, ent_tab, 0, lane);
  load_grp(Bv, adjb, ent_tab, 1, lane);
  proc_grp(A,  Wn, base, l0, l1, na);
  load_grp(A,  adjb, ent_tab, 2, lane);
  proc_grp(Bv, Wn, base, l0, l1, na);
  load_grp(Bv, adjb, ent_tab, 3, lane);
  proc_grp(A,  Wn, base, l0, l1, na);
  load_grp(A,  adjb, ent_tab, 4, lane);
  proc_grp(Bv, Wn, base, l0, l1, na);
  proc_grp(A,  Wn, base, l0, l1, na);
  na /= (l0 + l1);

  float h0 = b1[lane], h1 = 0.f, h2 = 0.f, h3 = 0.f;
#pragma unroll
  for (int d = 0; d < D; d += 4) {
    h0 = fmaf(readlane_f(na, d + 0), W1[(d + 0) * D + lane], h0);
    h1 = fmaf(readlane_f(na, d + 1), W1[(d + 1) * D + lane], h1);
    h2 = fmaf(readlane_f(na, d + 2), W1[(d + 2) * D + lane], h2);
    h3 = fmaf(readlane_f(na, d + 3), W1[(d + 3) * D + lane], h3);
  }
  const float h = fmaxf((h0 + h1) + (h2 + h3), 0.f);

  float r0 = b2[lane], r1 = 0.f, r2 = 0.f, r3 = 0.f;
#pragma unroll
  for (int d = 0; d < D; d += 4) {
    r0 = fmaf(readlane_f(h, d + 0), W2[(d + 0) * D + lane], r0);
    r1 = fmaf(readlane_f(h, d + 1), W2[(d + 1) * D + lane], r1);
    r2 = fmaf(readlane_f(h, d + 2), W2[(d + 2) * D + lane], r2);
    r3 = fmaf(readlane_f(h, d + 3), W2[(d + 3) * D + lane], r3);
  }
  const float r = (r0 + r1) + (r2 + r3);

  float f0 = cb[lane], f1 = 0.f, f2 = 0.f, f3 = 0.f;
#pragma unroll
  for (int k = 0; k < D; k += 4) {
    f0 = fmaf(readlane_f(item, k + 0), cW[(k + 0) * D + lane], f0);
    f1 = fmaf(readlane_f(item, k + 1), cW[(k + 1) * D + lane], f1);
    f2 = fmaf(readlane_f(item, k + 2), cW[(k + 2) * D + lane], f2);
    f3 = fmaf(readlane_f(item, k + 3), cW[(k + 3) * D + lane], f3);
  }
#pragma unroll
  for (int k = 0; k < D; k += 4) {
    f0 = fmaf(readlane_f(r, k + 0), cW[(D + k + 0) * D + lane], f0);
    f1 = fmaf(readlane_f(r, k + 1), cW[(D + k + 1) * D + lane], f1);
    f2 = fmaf(readlane_f(r, k + 2), cW[(D + k + 2) * D + lane], f2);
    f3 = fmaf(readlane_f(r, k + 3), cW[(D + k + 3) * D + lane], f3);
  }
  const float f = fmaxf((f0 + f1) + (f2 + f3), 0.f);

  const float sc = wave_sum64(fmaf(user, oWu, f * oWf));
  if (lane == 0) out[b] = sc + ob[0];
}

extern "C" void kernel_launch(void* const* d_in, const int* in_sizes, int n_in,
                              void* d_out, int out_size, void* d_ws, size_t ws_size,
                              hipStream_t stream) {
  const int*   user_idx = (const int*)d_in[0];
  const int*   item_idx = (const int*)d_in[1];
  const int*   adj      = (const int*)d_in[2];
  const float* user_tab = (const float*)d_in[3];
  const float* item_tab = (const float*)d_in[4];
  const float* ent_tab  = (const float*)d_in[5];
  const float* attn_W   = (const float*)d_in[6];
  const float* attn_b   = (const float*)d_in[7];
  const float* W1       = (const float*)d_in[8];
  const float* b1       = (const float*)d_in[9];
  const float* W2       = (const float*)d_in[10];
  const float* b2       = (const float*)d_in[11];
  const float* cW       = (const float*)d_in[12];
  const float* cb       = (const float*)d_in[13];
  const float* oW       = (const float*)d_in[14];
  const float* ob       = (const float*)d_in[15];
  float* out = (float*)d_out;

  const int B    = in_sizes[0];
  const int rows = in_sizes[5] / D;               // entity count
  const size_t need = (size_t)rows * sizeof(float);
  const int blocks = (B + 3) / 4;

  if (ws_size >= need) {
    float* proj = (float*)d_ws;
    const int waves   = (rows + GRP - 1) / GRP;
    const int pblocks = (waves + 3) / 4;
    ent_proj<<<pblocks, 256, 0, stream>>>(ent_tab, attn_W, proj, rows);
    kgat_main<<<blocks, 256, 0, stream>>>(user_idx, item_idx, adj,
                                          user_tab, item_tab, ent_tab, proj,
                                          attn_W, attn_b, W1, b1, W2, b2,
                                          cW, cb, oW, ob, out, B);
  } else {
    kgat_r3<<<blocks, 256, 0, stream>>>(user_idx, item_idx, adj,
                                        user_tab, item_tab, ent_tab,
                                        attn_W, attn_b, W1, b1, W2, b2,
                                        cW, cb, oW, ob, out, B);
  }
}